// Round 1
// baseline (490.105 us; speedup 1.0000x reference)
//
#include <hip/hip_runtime.h>

// Problem constants: DIM=1024, HEADS=16, DIM_HEAD=64, INNER=1024, B=2, N=2048.
// M = B*N = 4096 rows for all GEMMs; K = N_cols = 1024.

typedef unsigned short u16;
typedef __attribute__((ext_vector_type(8))) short bf16x8;  // 8 bf16 (4 VGPRs)
typedef __attribute__((ext_vector_type(4))) float f32x4;

#define DEV __device__ __forceinline__

DEV u16 f2bf(float f) {  // round-to-nearest-even f32 -> bf16
  unsigned u = __builtin_bit_cast(unsigned, f);
  u += 0x7FFFu + ((u >> 16) & 1u);
  return (u16)(u >> 16);
}
DEV float bf2f(u16 h) {
  unsigned u = ((unsigned)h) << 16;
  return __builtin_bit_cast(float, u);
}

DEV void gld16(const void* g, void* l) {  // async global->LDS, 16B/lane
  __builtin_amdgcn_global_load_lds(
      (const __attribute__((address_space(1))) unsigned int*)g,
      (__attribute__((address_space(3))) unsigned int*)l, 16, 0, 0);
}

// ---------------------------------------------------------------- cvt f32->bf16
__global__ __launch_bounds__(256) void cvt_kernel(const float* __restrict__ in,
                                                  u16* __restrict__ out) {
  const int i = blockIdx.x * 256 + threadIdx.x;  // one float4 per thread
  float4 v = ((const float4*)in)[i];
  u16 o[4] = {f2bf(v.x), f2bf(v.y), f2bf(v.z), f2bf(v.w)};
  ((ushort4*)out)[i] = *(const ushort4*)o;
}

// ------------------------------------------- weight transpose+convert (1024^2)
// Wt[c][k] = W[k][c], bf16 output. Makes the GEMM B operand k-contiguous.
__global__ __launch_bounds__(256) void wtT_kernel(const float* __restrict__ W,
                                                  u16* __restrict__ Wt) {
  __shared__ float tile[32][33];
  const int k0 = blockIdx.x * 32, c0 = blockIdx.y * 32;
  const int tx = threadIdx.x & 31, ty = threadIdx.x >> 5;  // 32 x 8
#pragma unroll
  for (int i = 0; i < 32; i += 8)
    tile[ty + i][tx] = W[(size_t)(k0 + ty + i) * 1024 + c0 + tx];
  __syncthreads();
#pragma unroll
  for (int i = 0; i < 32; i += 8)
    Wt[(size_t)(c0 + ty + i) * 1024 + k0 + tx] = f2bf(tile[tx][ty + i]);
}

// ------------------------------------------------------------------- GEMM 128^2
// C[m][n] = sum_k A[m][k] * Wt[n][k].   A: bf16 [M][K] row-major.
// EPI=0: write bf16 split-heads [b][h][n][d] (b=m>>11, n=m&2047, h=col>>6, d=col&63)
// EPI=1: write fp32 [m][1024] + bias
template <int EPI>
__global__ __launch_bounds__(256, 2) void gemm128(const u16* __restrict__ A,
                                                  const u16* __restrict__ Bt,
                                                  void* __restrict__ Cout,
                                                  const float* __restrict__ bias,
                                                  int M, int K) {
  __shared__ __align__(16) u16 Ab[128 * 32];
  __shared__ __align__(16) u16 Bb[128 * 32];
  const int tid = threadIdx.x;
  const int lane = tid & 63, wv = tid >> 6;
  const int g = lane >> 4, c = lane & 15;
  const int m0 = blockIdx.x * 128, n0 = blockIdx.y * 128;
  const int wr = (wv >> 1) * 64, wc = (wv & 1) * 64;
  const int srow = lane >> 2, scol = (lane & 3) * 8;  // staging map

  f32x4 acc[4][4];
#pragma unroll
  for (int i = 0; i < 4; i++)
#pragma unroll
    for (int j = 0; j < 4; j++) acc[i][j] = f32x4{0.f, 0.f, 0.f, 0.f};

  for (int k0 = 0; k0 < K; k0 += 32) {
    __syncthreads();
#pragma unroll
    for (int i = 0; i < 2; i++) {
      const int ch = wv + i * 4;  // wave-uniform chunk id; LDS dest = base+lane*16
      gld16(&A[(size_t)(m0 + ch * 16 + srow) * K + k0 + scol], &Ab[ch * 512]);
      gld16(&Bt[(size_t)(n0 + ch * 16 + srow) * K + k0 + scol], &Bb[ch * 512]);
    }
    __syncthreads();
    bf16x8 af[4], bf[4];
#pragma unroll
    for (int mi = 0; mi < 4; mi++)
      af[mi] = *(const bf16x8*)&Ab[(wr + mi * 16 + c) * 32 + g * 8];
#pragma unroll
    for (int ni = 0; ni < 4; ni++)
      bf[ni] = *(const bf16x8*)&Bb[(wc + ni * 16 + c) * 32 + g * 8];
#pragma unroll
    for (int mi = 0; mi < 4; mi++)
#pragma unroll
      for (int ni = 0; ni < 4; ni++)
        acc[mi][ni] = __builtin_amdgcn_mfma_f32_16x16x32_bf16(af[mi], bf[ni],
                                                              acc[mi][ni], 0, 0, 0);
  }

#pragma unroll
  for (int mi = 0; mi < 4; mi++)
#pragma unroll
    for (int ni = 0; ni < 4; ni++)
#pragma unroll
      for (int r = 0; r < 4; r++) {
        const int m = m0 + wr + mi * 16 + g * 4 + r;  // C row = (lane>>4)*4+reg
        const int n = n0 + wc + ni * 16 + c;          // C col = lane&15
        if constexpr (EPI == 0) {
          const int b = m >> 11, nn = m & 2047, h = n >> 6, d = n & 63;
          ((u16*)Cout)[((((size_t)(b * 16 + h)) * 2048 + nn) << 6) + d] =
              f2bf(acc[mi][ni][r]);
        } else {
          ((float*)Cout)[(size_t)m * 1024 + n] = acc[mi][ni][r] + bias[n];
        }
      }
}

// ------------------------------------------------------- spatial flash attention
// Per (b,h): out1 = softmax(z1 @ yh^T * 0.125) @ xh ; written straight into
// comb[b][n][h*64+d] (bf16). Q=z1, K=yh, V=xh, all [bh][2048][64] bf16.
__global__ __launch_bounds__(256, 2) void attn_sp(const u16* __restrict__ Q,
                                                  const u16* __restrict__ Kt,
                                                  const u16* __restrict__ V,
                                                  u16* __restrict__ comb) {
  __shared__ __align__(16) u16 Kld[64 * 64];    // XOR-swizzled [key][64]
  __shared__ __align__(16) u16 Vt[64 * 72];     // transposed [d][key], pad 72
  __shared__ __align__(16) u16 Pl[4][16 * 72];  // per-wave P [qrow][key], pad 72
  const int tid = threadIdx.x, lane = tid & 63, wv = tid >> 6;
  const int g = lane >> 4, c = lane & 15;
  const int bh = blockIdx.x >> 5, qt = blockIdx.x & 31;
  const size_t base = (size_t)bh * (2048 * 64);
  const int q0 = qt * 64 + wv * 16;

  bf16x8 qf[2];
#pragma unroll
  for (int kf = 0; kf < 2; kf++)
    qf[kf] = *(const bf16x8*)&Q[base + (size_t)(q0 + c) * 64 + kf * 32 + g * 8];

  f32x4 acc[4];
#pragma unroll
  for (int df = 0; df < 4; df++) acc[df] = f32x4{0.f, 0.f, 0.f, 0.f};
  float mrow[4] = {-1e30f, -1e30f, -1e30f, -1e30f};
  float lrow[4] = {0.f, 0.f, 0.f, 0.f};

  const int skey = tid >> 3, sch = tid & 7;  // staging: key, 16B-chunk
  for (int kv = 0; kv < 2048; kv += 64) {
    __syncthreads();
#pragma unroll
    for (int i = 0; i < 2; i++) {
      const int key = i * 32 + skey;
      int4 kvec = *(const int4*)&Kt[base + (size_t)(kv + key) * 64 + sch * 8];
      *(int4*)((char*)Kld + ((key * 128 + sch * 16) ^ ((key & 7) << 4))) = kvec;
      int4 vvec = *(const int4*)&V[base + (size_t)(kv + key) * 64 + sch * 8];
      const u16* vs = (const u16*)&vvec;
#pragma unroll
      for (int j = 0; j < 8; j++) Vt[(sch * 8 + j) * 72 + key] = vs[j];
    }
    __syncthreads();

    // S = Q K^T  (rows = q, cols = key)
    f32x4 s[4];
#pragma unroll
    for (int nf = 0; nf < 4; nf++) {
      s[nf] = f32x4{0.f, 0.f, 0.f, 0.f};
      const int key = nf * 16 + c;
#pragma unroll
      for (int kf = 0; kf < 2; kf++) {
        bf16x8 kfr = *(const bf16x8*)((const char*)Kld +
                                      ((key * 128 + kf * 64 + g * 16) ^ ((key & 7) << 4)));
        s[nf] = __builtin_amdgcn_mfma_f32_16x16x32_bf16(qf[kf], kfr, s[nf], 0, 0, 0);
      }
    }

    // online softmax per q-row (row = g*4+r, spread over 16 lanes x 4 nf)
#pragma unroll
    for (int r = 0; r < 4; r++) {
      float s0 = s[0][r] * 0.125f, s1 = s[1][r] * 0.125f;
      float s2 = s[2][r] * 0.125f, s3 = s[3][r] * 0.125f;
      float mt = fmaxf(fmaxf(s0, s1), fmaxf(s2, s3));
#pragma unroll
      for (int off = 1; off < 16; off <<= 1) mt = fmaxf(mt, __shfl_xor(mt, off));
      const float mnew = fmaxf(mrow[r], mt);
      const float fsc = __expf(mrow[r] - mnew);
      mrow[r] = mnew;
      const float p0 = __expf(s0 - mnew), p1 = __expf(s1 - mnew);
      const float p2 = __expf(s2 - mnew), p3 = __expf(s3 - mnew);
      float ps = p0 + p1 + p2 + p3;
#pragma unroll
      for (int off = 1; off < 16; off <<= 1) ps += __shfl_xor(ps, off);
      lrow[r] = lrow[r] * fsc + ps;
#pragma unroll
      for (int df = 0; df < 4; df++) acc[df][r] *= fsc;
      u16* prow = &Pl[wv][(g * 4 + r) * 72];
      prow[c] = f2bf(p0);
      prow[16 + c] = f2bf(p1);
      prow[32 + c] = f2bf(p2);
      prow[48 + c] = f2bf(p3);
    }

    // O += P @ V
#pragma unroll
    for (int kk = 0; kk < 2; kk++) {
      bf16x8 pf = *(const bf16x8*)&Pl[wv][c * 72 + kk * 32 + g * 8];
#pragma unroll
      for (int df = 0; df < 4; df++) {
        bf16x8 vf = *(const bf16x8*)&Vt[(df * 16 + c) * 72 + kk * 32 + g * 8];
        acc[df] = __builtin_amdgcn_mfma_f32_16x16x32_bf16(pf, vf, acc[df], 0, 0, 0);
      }
    }
  }

  const int b = bh >> 4, h = bh & 15;
#pragma unroll
  for (int r = 0; r < 4; r++) {
    const float inv = 1.f / lrow[r];
    const int n = q0 + g * 4 + r;
    const size_t off = ((size_t)(b * 2048 + n)) * 1024 + h * 64;
#pragma unroll
    for (int df = 0; df < 4; df++)
      comb[off + df * 16 + c] = f2bf(acc[df][r] * inv);
  }
}

// --------------------------------------------- channel attention: partial scores
// part[bh][sl][i][j] = sum_{n in slice} xh[n][i] * z2[n][j]  (fp32)
__global__ __launch_bounds__(256) void chan_part(const u16* __restrict__ Xh,
                                                 const u16* __restrict__ Z2,
                                                 float* __restrict__ part) {
  const int bh = blockIdx.y, sl = blockIdx.x;
  const size_t base = (size_t)bh * (2048 * 64);
  const int ti = threadIdx.x >> 4, tj = threadIdx.x & 15;
  float a[4][4];
#pragma unroll
  for (int u = 0; u < 4; u++)
#pragma unroll
    for (int v = 0; v < 4; v++) a[u][v] = 0.f;
  const int n0 = sl * 256;
  for (int n = 0; n < 256; n++) {
    ushort4 xv = *(const ushort4*)&Xh[base + (size_t)(n0 + n) * 64 + ti * 4];
    ushort4 zv = *(const ushort4*)&Z2[base + (size_t)(n0 + n) * 64 + tj * 4];
    float xf[4] = {bf2f(xv.x), bf2f(xv.y), bf2f(xv.z), bf2f(xv.w)};
    float zf[4] = {bf2f(zv.x), bf2f(zv.y), bf2f(zv.z), bf2f(zv.w)};
#pragma unroll
    for (int u = 0; u < 4; u++)
#pragma unroll
      for (int v = 0; v < 4; v++) a[u][v] += xf[u] * zf[v];
  }
  float* dst = part + ((size_t)bh * 8 + sl) * 4096;
#pragma unroll
  for (int u = 0; u < 4; u++)
#pragma unroll
    for (int v = 0; v < 4; v++) dst[(ti * 4 + u) * 64 + tj * 4 + v] = a[u][v];
}

// secm[bh][i][j] = softmax_j( sum_sl part * (1/256) )
__global__ __launch_bounds__(64) void chan_sm(const float* __restrict__ part,
                                              float* __restrict__ secm) {
  const int bh = blockIdx.x, r = threadIdx.x;  // 64 threads = 64 rows
  float v[64];
#pragma unroll
  for (int j = 0; j < 64; j++) v[j] = 0.f;
  for (int sl = 0; sl < 8; sl++) {
    const float* p = part + ((size_t)bh * 8 + sl) * 4096 + r * 64;
#pragma unroll
    for (int j = 0; j < 64; j++) v[j] += p[j];
  }
  float mx = -1e30f;
#pragma unroll
  for (int j = 0; j < 64; j++) {
    v[j] *= (1.f / 256.f);  // scale(0.125) / (n/d = 32)
    mx = fmaxf(mx, v[j]);
  }
  float sum = 0.f;
#pragma unroll
  for (int j = 0; j < 64; j++) {
    v[j] = __expf(v[j] - mx);
    sum += v[j];
  }
  const float inv = 1.f / sum;
  float* o = secm + (size_t)bh * 4096 + r * 64;
#pragma unroll
  for (int j = 0; j < 64; j++) o[j] = v[j] * inv;
}

// comb[b][n][h*64+j] += sum_i yh[bh][n][i] * secm[bh][i][j]   (wave per row)
__global__ __launch_bounds__(256) void combine_k(const u16* __restrict__ Yh,
                                                 const float* __restrict__ secm,
                                                 u16* __restrict__ comb) {
  const int tid = threadIdx.x, lane = tid & 63, wv = tid >> 6;
  const size_t row = (size_t)blockIdx.x * 4 + wv;  // bh*2048 + n
  const int bh = (int)(row >> 11), n = (int)(row & 2047);
  const int b = bh >> 4, h = bh & 15;
  const float yv = bf2f(Yh[row * 64 + lane]);
  const float* S = secm + (size_t)bh * 4096;
  float acc2 = 0.f;
#pragma unroll 8
  for (int i = 0; i < 64; i++) acc2 += __shfl(yv, i) * S[i * 64 + lane];
  const size_t off = ((size_t)(b * 2048 + n)) * 1024 + (size_t)h * 64 + lane;
  comb[off] = f2bf(bf2f(comb[off]) + acc2);
}

// ---------------------------------------------------------------------- launch
extern "C" void kernel_launch(void* const* d_in, const int* in_sizes, int n_in,
                              void* d_out, int out_size, void* d_ws, size_t ws_size,
                              hipStream_t stream) {
  (void)in_sizes; (void)n_in; (void)out_size; (void)ws_size;
  const float* x = (const float*)d_in[0];
  const float* y = (const float*)d_in[1];
  const float* z = (const float*)d_in[2];
  const float* w_sa1 = (const float*)d_in[3];
  const float* w_sa2 = (const float*)d_in[4];
  const float* w_se1 = (const float*)d_in[5];
  const float* w_se2 = (const float*)d_in[6];
  const float* w_out = (const float*)d_in[7];
  const float* b_out = (const float*)d_in[8];

  char* w = (char*)d_ws;
  const size_t MB = (size_t)1 << 20;
  // Aliased workspace plan (66 MB total):
  u16* xb = (u16*)(w + 0);            // x bf16; later reused as comb
  u16* comb = xb;                     // attention output + out2 (bf16, [b][n][1024])
  u16* yb = (u16*)(w + 8 * MB);       // y bf16; later reused as chan partials
  float* scpart = (float*)(w + 8 * MB);
  u16* zb = (u16*)(w + 16 * MB);      // z bf16; later reused as secm
  float* secm = (float*)(w + 16 * MB);
  u16* Wt1 = (u16*)(w + 24 * MB);
  u16* Wt2 = (u16*)(w + 26 * MB);
  u16* Wt3 = (u16*)(w + 28 * MB);
  u16* Wt4 = (u16*)(w + 30 * MB);
  u16* Wto = (u16*)(w + 32 * MB);
  u16* z1 = (u16*)(w + 34 * MB);      // [bh][2048][64] bf16 projections
  u16* yh = (u16*)(w + 42 * MB);
  u16* xh = (u16*)(w + 50 * MB);
  u16* z2 = (u16*)(w + 58 * MB);

  // 1) convert inputs to bf16
  cvt_kernel<<<4096, 256, 0, stream>>>(x, xb);
  cvt_kernel<<<4096, 256, 0, stream>>>(y, yb);
  cvt_kernel<<<4096, 256, 0, stream>>>(z, zb);
  // 2) transpose+convert weights
  dim3 tg(32, 32);
  wtT_kernel<<<tg, 256, 0, stream>>>(w_sa1, Wt1);
  wtT_kernel<<<tg, 256, 0, stream>>>(w_sa2, Wt2);
  wtT_kernel<<<tg, 256, 0, stream>>>(w_se1, Wt3);
  wtT_kernel<<<tg, 256, 0, stream>>>(w_se2, Wt4);
  wtT_kernel<<<tg, 256, 0, stream>>>(w_out, Wto);
  // 3) projections (split-heads bf16 out)
  dim3 gg(32, 8);
  gemm128<0><<<gg, 256, 0, stream>>>(zb, Wt1, z1, nullptr, 4096, 1024);
  gemm128<0><<<gg, 256, 0, stream>>>(yb, Wt2, yh, nullptr, 4096, 1024);
  gemm128<0><<<gg, 256, 0, stream>>>(xb, Wt3, xh, nullptr, 4096, 1024);
  gemm128<0><<<gg, 256, 0, stream>>>(zb, Wt4, z2, nullptr, 4096, 1024);
  // 4) spatial attention -> comb (overwrites xb region; xb is dead now)
  attn_sp<<<1024, 256, 0, stream>>>(z1, yh, xh, comb);
  // 5) channel attention
  chan_part<<<dim3(8, 32), 256, 0, stream>>>(xh, z2, scpart);
  chan_sm<<<32, 64, 0, stream>>>(scpart, secm);
  combine_k<<<16384, 256, 0, stream>>>(yh, secm, comb);
  // 6) output projection + bias -> d_out (fp32)
  gemm128<1><<<gg, 256, 0, stream>>>(comb, Wto, d_out, b_out, 4096, 1024);
}

// Round 8
// 432.631 us; speedup vs baseline: 1.1328x; 1.1328x over previous
//
#include <hip/hip_runtime.h>

// Problem constants: DIM=1024, HEADS=16, DIM_HEAD=64, INNER=1024, B=2, N=2048.
// M = B*N = 4096 rows for all GEMMs; K = N_cols = 1024.

typedef unsigned short u16;
typedef unsigned int u32;
typedef __attribute__((ext_vector_type(8))) short bf16x8;  // 8 bf16 (4 VGPRs)
typedef __attribute__((ext_vector_type(4))) float f32x4;

#define DEV __device__ __forceinline__

DEV u16 f2bf(float f) {  // round-to-nearest-even f32 -> bf16
  unsigned u = __builtin_bit_cast(unsigned, f);
  u += 0x7FFFu + ((u >> 16) & 1u);
  return (u16)(u >> 16);
}
DEV float bf2f(u16 h) {
  unsigned u = ((unsigned)h) << 16;
  return __builtin_bit_cast(float, u);
}

DEV void gld16(const void* g, void* l) {  // async global->LDS, 16B/lane
  __builtin_amdgcn_global_load_lds(
      (const __attribute__((address_space(1))) unsigned int*)g,
      (__attribute__((address_space(3))) unsigned int*)l, 16, 0, 0);
}

union B8 {
  u32 w[4];
  bf16x8 v;
};

// ---------------------------------------------------------------- cvt f32->bf16
__global__ __launch_bounds__(256) void cvt_kernel(const float* __restrict__ in,
                                                  u16* __restrict__ out) {
  const int i = blockIdx.x * 256 + threadIdx.x;  // one float4 per thread
  float4 v = ((const float4*)in)[i];
  u16 o[4] = {f2bf(v.x), f2bf(v.y), f2bf(v.z), f2bf(v.w)};
  ((ushort4*)out)[i] = *(const ushort4*)o;
}

// ------------------------------------------- weight transpose+convert (1024^2)
__global__ __launch_bounds__(256) void wtT_kernel(const float* __restrict__ W,
                                                  u16* __restrict__ Wt) {
  __shared__ float tile[32][33];
  const int k0 = blockIdx.x * 32, c0 = blockIdx.y * 32;
  const int tx = threadIdx.x & 31, ty = threadIdx.x >> 5;  // 32 x 8
#pragma unroll
  for (int i = 0; i < 32; i += 8)
    tile[ty + i][tx] = W[(size_t)(k0 + ty + i) * 1024 + c0 + tx];
  __syncthreads();
#pragma unroll
  for (int i = 0; i < 32; i += 8)
    Wt[(size_t)(c0 + ty + i) * 1024 + k0 + tx] = f2bf(tile[tx][ty + i]);
}

// ------------------------------------------------------------------- GEMM 128^2
// C[m][n] = sum_k A[m][k] * Wt[n][k].   A: bf16 [M][K] row-major.
// EPI=0: write bf16*oscale split-heads [b][h][n][d]; EPI=1: fp32 [m][1024]+bias
template <int EPI>
__global__ __launch_bounds__(256, 2) void gemm128(const u16* __restrict__ A,
                                                  const u16* __restrict__ Bt,
                                                  void* __restrict__ Cout,
                                                  const float* __restrict__ bias,
                                                  int M, int K, float oscale) {
  __shared__ __align__(16) u16 Ab[128 * 32];
  __shared__ __align__(16) u16 Bb[128 * 32];
  const int tid = threadIdx.x;
  const int lane = tid & 63, wv = tid >> 6;
  const int g = lane >> 4, c = lane & 15;
  const int m0 = blockIdx.x * 128, n0 = blockIdx.y * 128;
  const int wr = (wv >> 1) * 64, wc = (wv & 1) * 64;
  const int srow = lane >> 2, scol = (lane & 3) * 8;  // staging map

  f32x4 acc[4][4];
#pragma unroll
  for (int i = 0; i < 4; i++)
#pragma unroll
    for (int j = 0; j < 4; j++) acc[i][j] = f32x4{0.f, 0.f, 0.f, 0.f};

  for (int k0 = 0; k0 < K; k0 += 32) {
    __syncthreads();
#pragma unroll
    for (int i = 0; i < 2; i++) {
      const int ch = wv + i * 4;  // wave-uniform chunk id; LDS dest = base+lane*16
      gld16(&A[(size_t)(m0 + ch * 16 + srow) * K + k0 + scol], &Ab[ch * 512]);
      gld16(&Bt[(size_t)(n0 + ch * 16 + srow) * K + k0 + scol], &Bb[ch * 512]);
    }
    __syncthreads();
    bf16x8 af[4], bf[4];
#pragma unroll
    for (int mi = 0; mi < 4; mi++)
      af[mi] = *(const bf16x8*)&Ab[(wr + mi * 16 + c) * 32 + g * 8];
#pragma unroll
    for (int ni = 0; ni < 4; ni++)
      bf[ni] = *(const bf16x8*)&Bb[(wc + ni * 16 + c) * 32 + g * 8];
#pragma unroll
    for (int mi = 0; mi < 4; mi++)
#pragma unroll
      for (int ni = 0; ni < 4; ni++)
        acc[mi][ni] = __builtin_amdgcn_mfma_f32_16x16x32_bf16(af[mi], bf[ni],
                                                              acc[mi][ni], 0, 0, 0);
  }

#pragma unroll
  for (int mi = 0; mi < 4; mi++)
#pragma unroll
    for (int ni = 0; ni < 4; ni++)
#pragma unroll
      for (int r = 0; r < 4; r++) {
        const int m = m0 + wr + mi * 16 + g * 4 + r;  // C row = (lane>>4)*4+reg
        const int n = n0 + wc + ni * 16 + c;          // C col = lane&15
        if constexpr (EPI == 0) {
          const int b = m >> 11, nn = m & 2047, h = n >> 6, d = n & 63;
          ((u16*)Cout)[((((size_t)(b * 16 + h)) * 2048 + nn) << 6) + d] =
              f2bf(acc[mi][ni][r] * oscale);
        } else {
          ((float*)Cout)[(size_t)m * 1024 + n] = acc[mi][ni][r] + bias[n];
        }
      }
}

// ------------------------------------------------------- spatial flash attention
// Swapped-QK flash attention. Per (b,h): out1 = softmax(z1 yh^T)·xh  (scale
// pre-folded into z1). Q=z1(scaled), K=yh, V=xh: [bh][2048][64] bf16.
// Block = 128 q rows (4 waves x 32 q). KVB=64. S^T = mfma(Kfrag, Qfrag) so each
// lane holds a q-row's scores -> in-register softmax; P rebuilt via bpermute.
// LDS swizzle: chunk ^= (row&7) ^ ((row>>3)&7)  (conflict-free for b128 reads
// AND the scalar V-transpose stores; G21: gld16 K dest linear, source pre-swz).
__global__ __launch_bounds__(256, 2) void attn_sp(const u16* __restrict__ Q,
                                                  const u16* __restrict__ K,
                                                  const u16* __restrict__ V,
                                                  u16* __restrict__ comb) {
  __shared__ __align__(16) u16 Kld[2][4096];
  __shared__ __align__(16) u16 Vld[2][4096];
  const int tid = threadIdx.x, lane = tid & 63, wv = tid >> 6;
  const int g = lane >> 4, c = lane & 15;
  const int bh = blockIdx.x & 31, qt = blockIdx.x >> 5;  // same-bh blocks -> same XCD
  const size_t base = (size_t)bh * (2048 * 64);
  const int q0 = qt * 128 + wv * 32;
  const u16* Qp = Q + base;
  const u16* Kp = K + base;
  const u16* Vp = V + base;

  // Q fragments (B-operand): lane(c,g) holds Q[q0+qb*16+c][kf*32+g*8 ..+7]
  bf16x8 qf[2][2];
#pragma unroll
  for (int qb = 0; qb < 2; qb++)
#pragma unroll
    for (int kf = 0; kf < 2; kf++)
      qf[qb][kf] =
          *(const bf16x8*)&Qp[(size_t)(q0 + qb * 16 + c) * 64 + kf * 32 + g * 8];

  // K staging: gld16 linear dest; source chunk pre-swizzled.
  int ksrc[2], kbas[2];
#pragma unroll
  for (int t2 = 0; t2 < 2; t2++) {
    const int r = wv * 16 + t2 * 8 + (lane >> 3);
    const int ul = (lane & 7) ^ (lane >> 3) ^ ((wv * 2 + t2) & 7);
    ksrc[t2] = r * 64 + ul * 8;       // u16 elems within K tile
    kbas[t2] = wv * 1024 + t2 * 512;  // u16 elems, wave-uniform LDS base
  }
  // V staging: each 8-lane group reads one full key row (perfect coalescing).
  const int vd0 = (lane & 7) * 8;  // 8 consecutive d per lane
  const int vkey0 = wv * 8 + (lane >> 3), vkey1 = 32 + vkey0;
  const int vx = lane & 7;  // = (d>>3)&7 for all 8 stored elems

  f32x4 acc[2][4];
  float mrow[2] = {-3e38f, -3e38f}, lrow[2] = {0.f, 0.f};
#pragma unroll
  for (int qb = 0; qb < 2; qb++)
#pragma unroll
    for (int df = 0; df < 4; df++) acc[qb][df] = f32x4{0.f, 0.f, 0.f, 0.f};

  // prologue: tile 0 in flight
  gld16(Kp + ksrc[0], &Kld[0][kbas[0]]);
  gld16(Kp + ksrc[1], &Kld[0][kbas[1]]);
  int4 vv0 = *(const int4*)&Vp[(size_t)vkey0 * 64 + vd0];
  int4 vv1 = *(const int4*)&Vp[(size_t)vkey1 * 64 + vd0];

  for (int t = 0; t < 32; ++t) {
    const int p = t & 1;
    u16* Kb = Kld[p];
    u16* Vb = Vld[p];
    __syncthreads();  // K[p] landed (vmcnt drain), prev tile's readers done

    // V transpose-store (row=d layout, swizzled): conflict-free per 8-lane group
    {
      const u16* vs = (const u16*)&vv0;
      const int ui = wv, si = vkey0 & 7;
#pragma unroll
      for (int j = 0; j < 8; j++)
        Vb[(vd0 + j) * 64 + (((ui ^ j ^ vx) & 7) << 3) + si] = vs[j];
    }
    {
      const u16* vs = (const u16*)&vv1;
      const int ui = 4 + wv, si = vkey1 & 7;
#pragma unroll
      for (int j = 0; j < 8; j++)
        Vb[(vd0 + j) * 64 + (((ui ^ j ^ vx) & 7) << 3) + si] = vs[j];
    }
    // prefetch tile t+1 (overlaps this tile's compute)
    if (t < 31) {
      const u16* Kn = Kp + (t + 1) * 4096;
      gld16(Kn + ksrc[0], &Kld[p ^ 1][kbas[0]]);
      gld16(Kn + ksrc[1], &Kld[p ^ 1][kbas[1]]);
      const u16* Vn = Vp + (t + 1) * 4096;
      vv0 = *(const int4*)&Vn[vkey0 * 64 + vd0];
      vv1 = *(const int4*)&Vn[vkey1 * 64 + vd0];
    }

    // S^T[key][q] = mfma(Kfrag, Qfrag): lane(c,g) gets key=nf*16+g*4+r, q=c
    f32x4 st[2][4];
#pragma unroll
    for (int qb = 0; qb < 2; qb++)
#pragma unroll
      for (int nf = 0; nf < 4; nf++) st[qb][nf] = f32x4{0.f, 0.f, 0.f, 0.f};
#pragma unroll
    for (int nf = 0; nf < 4; nf++)
#pragma unroll
      for (int kf = 0; kf < 2; kf++) {
        const int phys = (kf * 4 + g) ^ (c & 7) ^ ((nf * 2 + (c >> 3)) & 7);
        bf16x8 af =
            *(const bf16x8*)((const char*)Kb + ((nf * 16 + c) << 7) + (phys << 4));
        st[0][nf] = __builtin_amdgcn_mfma_f32_16x16x32_bf16(af, qf[0][kf],
                                                            st[0][nf], 0, 0, 0);
        st[1][nf] = __builtin_amdgcn_mfma_f32_16x16x32_bf16(af, qf[1][kf],
                                                            st[1][nf], 0, 0, 0);
      }

    // in-register online softmax (per lane = per q-row; g-replicated)
    u32 pk[2][4][2];
#pragma unroll
    for (int qb = 0; qb < 2; qb++) {
      float mt = -3e38f;
#pragma unroll
      for (int nf = 0; nf < 4; nf++)
#pragma unroll
        for (int r = 0; r < 4; r++) mt = fmaxf(mt, st[qb][nf][r]);
      mt = fmaxf(mt, __shfl_xor(mt, 16));
      mt = fmaxf(mt, __shfl_xor(mt, 32));
      const float mnew = fmaxf(mrow[qb], mt);
      const float fsc = __expf(mrow[qb] - mnew);
      mrow[qb] = mnew;
      float p_[4][4];
      float ps = 0.f;
#pragma unroll
      for (int nf = 0; nf < 4; nf++)
#pragma unroll
        for (int r = 0; r < 4; r++) {
          p_[nf][r] = __expf(st[qb][nf][r] - mnew);
          ps += p_[nf][r];
        }
      ps += __shfl_xor(ps, 16);
      ps += __shfl_xor(ps, 32);
      lrow[qb] = lrow[qb] * fsc + ps;
      // O-rescale: O rows live on (g,r); fetch fsc of q-row 4g+r from lane 4g+r
      float fo[4];
#pragma unroll
      for (int r = 0; r < 4; r++) fo[r] = __shfl(fsc, 4 * g + r);
#pragma unroll
      for (int df = 0; df < 4; df++)
#pragma unroll
        for (int r = 0; r < 4; r++) acc[qb][df][r] *= fo[r];
#pragma unroll
      for (int nf = 0; nf < 4; nf++) {
        pk[qb][nf][0] = (u32)f2bf(p_[nf][0]) | ((u32)f2bf(p_[nf][1]) << 16);
        pk[qb][nf][1] = (u32)f2bf(p_[nf][2]) | ((u32)f2bf(p_[nf][3]) << 16);
      }
    }
    __syncthreads();  // Vt[p] complete (all waves) before PV reads

    // PV: rebuild P A-fragments in-register (bpermute), O += P·V
#pragma unroll
    for (int kk = 0; kk < 2; kk++) {
      const int srcA = c + ((g & 1) << 5);
      const int srcB = srcA + 16;
      const bool hi = g >= 2;  // selects nf = 2kk+1
      bf16x8 pf[2];
#pragma unroll
      for (int qb = 0; qb < 2; qb++) {
        B8 u;
        u32 a0 = (u32)__shfl((int)pk[qb][2 * kk + 0][0], srcA);
        u32 a1 = (u32)__shfl((int)pk[qb][2 * kk + 1][0], srcA);
        u.w[0] = hi ? a1 : a0;
        a0 = (u32)__shfl((int)pk[qb][2 * kk + 0][1], srcA);
        a1 = (u32)__shfl((int)pk[qb][2 * kk + 1][1], srcA);
        u.w[1] = hi ? a1 : a0;
        a0 = (u32)__shfl((int)pk[qb][2 * kk + 0][0], srcB);
        a1 = (u32)__shfl((int)pk[qb][2 * kk + 1][0], srcB);
        u.w[2] = hi ? a1 : a0;
        a0 = (u32)__shfl((int)pk[qb][2 * kk + 0][1], srcB);
        a1 = (u32)__shfl((int)pk[qb][2 * kk + 1][1], srcB);
        u.w[3] = hi ? a1 : a0;
        pf[qb] = u.v;
      }
#pragma unroll
      for (int df = 0; df < 4; df++) {
        const int phys = (kk * 4 + g) ^ (c & 7) ^ ((df * 2 + (c >> 3)) & 7);
        bf16x8 vf =
            *(const bf16x8*)((const char*)Vb + ((df * 16 + c) << 7) + (phys << 4));
        acc[0][df] = __builtin_amdgcn_mfma_f32_16x16x32_bf16(pf[0], vf,
                                                             acc[0][df], 0, 0, 0);
        acc[1][df] = __builtin_amdgcn_mfma_f32_16x16x32_bf16(pf[1], vf,
                                                             acc[1][df], 0, 0, 0);
      }
    }
  }

  const int b = bh >> 4, h = bh & 15;
#pragma unroll
  for (int qb = 0; qb < 2; qb++)
#pragma unroll
    for (int r = 0; r < 4; r++) {
      const float lr = __shfl(lrow[qb], 4 * g + r);
      const float inv = 1.f / lr;
      const int n = q0 + qb * 16 + g * 4 + r;
      const size_t off = ((size_t)(b * 2048 + n)) * 1024 + h * 64;
#pragma unroll
      for (int df = 0; df < 4; df++)
        comb[off + df * 16 + c] = f2bf(acc[qb][df][r] * inv);
    }
}

// --------------------------------------------- channel attention: partial scores
__global__ __launch_bounds__(256) void chan_part(const u16* __restrict__ Xh,
                                                 const u16* __restrict__ Z2,
                                                 float* __restrict__ part) {
  const int bh = blockIdx.y, sl = blockIdx.x;
  const size_t base = (size_t)bh * (2048 * 64);
  const int ti = threadIdx.x >> 4, tj = threadIdx.x & 15;
  float a[4][4];
#pragma unroll
  for (int u = 0; u < 4; u++)
#pragma unroll
    for (int v = 0; v < 4; v++) a[u][v] = 0.f;
  const int n0 = sl * 256;
  for (int n = 0; n < 256; n++) {
    ushort4 xv = *(const ushort4*)&Xh[base + (size_t)(n0 + n) * 64 + ti * 4];
    ushort4 zv = *(const ushort4*)&Z2[base + (size_t)(n0 + n) * 64 + tj * 4];
    float xf[4] = {bf2f(xv.x), bf2f(xv.y), bf2f(xv.z), bf2f(xv.w)};
    float zf[4] = {bf2f(zv.x), bf2f(zv.y), bf2f(zv.z), bf2f(zv.w)};
#pragma unroll
    for (int u = 0; u < 4; u++)
#pragma unroll
      for (int v = 0; v < 4; v++) a[u][v] += xf[u] * zf[v];
  }
  float* dst = part + ((size_t)bh * 8 + sl) * 4096;
#pragma unroll
  for (int u = 0; u < 4; u++)
#pragma unroll
    for (int v = 0; v < 4; v++) dst[(ti * 4 + u) * 64 + tj * 4 + v] = a[u][v];
}

// secm[bh][i][j] = softmax_j( sum_sl part * (1/256) )
__global__ __launch_bounds__(64) void chan_sm(const float* __restrict__ part,
                                              float* __restrict__ secm) {
  const int bh = blockIdx.x, r = threadIdx.x;  // 64 threads = 64 rows
  float v[64];
#pragma unroll
  for (int j = 0; j < 64; j++) v[j] = 0.f;
  for (int sl = 0; sl < 8; sl++) {
    const float* p = part + ((size_t)bh * 8 + sl) * 4096 + r * 64;
#pragma unroll
    for (int j = 0; j < 64; j++) v[j] += p[j];
  }
  float mx = -1e30f;
#pragma unroll
  for (int j = 0; j < 64; j++) {
    v[j] *= (1.f / 256.f);  // scale(0.125) / (n/d = 32)
    mx = fmaxf(mx, v[j]);
  }
  float sum = 0.f;
#pragma unroll
  for (int j = 0; j < 64; j++) {
    v[j] = __expf(v[j] - mx);
    sum += v[j];
  }
  const float inv = 1.f / sum;
  float* o = secm + (size_t)bh * 4096 + r * 64;
#pragma unroll
  for (int j = 0; j < 64; j++) o[j] = v[j] * inv;
}

// comb[b][n][h*64+j] += sum_i yh[bh][n][i] * secm[bh][i][j]   (wave per row)
__global__ __launch_bounds__(256) void combine_k(const u16* __restrict__ Yh,
                                                 const float* __restrict__ secm,
                                                 u16* __restrict__ comb) {
  const int tid = threadIdx.x, lane = tid & 63, wv = tid >> 6;
  const size_t row = (size_t)blockIdx.x * 4 + wv;  // bh*2048 + n
  const int bh = (int)(row >> 11), n = (int)(row & 2047);
  const int b = bh >> 4, h = bh & 15;
  const float yv = bf2f(Yh[row * 64 + lane]);
  const float* S = secm + (size_t)bh * 4096;
  float acc2 = 0.f;
#pragma unroll 8
  for (int i = 0; i < 64; i++) acc2 += __shfl(yv, i) * S[i * 64 + lane];
  const size_t off = ((size_t)(b * 2048 + n)) * 1024 + (size_t)h * 64 + lane;
  comb[off] = f2bf(bf2f(comb[off]) + acc2);
}

// ---------------------------------------------------------------------- launch
extern "C" void kernel_launch(void* const* d_in, const int* in_sizes, int n_in,
                              void* d_out, int out_size, void* d_ws, size_t ws_size,
                              hipStream_t stream) {
  (void)in_sizes; (void)n_in; (void)out_size; (void)ws_size;
  const float* x = (const float*)d_in[0];
  const float* y = (const float*)d_in[1];
  const float* z = (const float*)d_in[2];
  const float* w_sa1 = (const float*)d_in[3];
  const float* w_sa2 = (const float*)d_in[4];
  const float* w_se1 = (const float*)d_in[5];
  const float* w_se2 = (const float*)d_in[6];
  const float* w_out = (const float*)d_in[7];
  const float* b_out = (const float*)d_in[8];

  char* w = (char*)d_ws;
  const size_t MB = (size_t)1 << 20;
  u16* xb = (u16*)(w + 0);        // x bf16; later reused as comb
  u16* comb = xb;                 // attention out1+out2 (bf16, [b][n][1024])
  u16* yb = (u16*)(w + 8 * MB);   // y bf16; later reused as chan partials
  float* scpart = (float*)(w + 8 * MB);
  u16* zb = (u16*)(w + 16 * MB);  // z bf16; later reused as secm
  float* secm = (float*)(w + 16 * MB);
  u16* Wt1 = (u16*)(w + 24 * MB);
  u16* Wt2 = (u16*)(w + 26 * MB);
  u16* Wt3 = (u16*)(w + 28 * MB);
  u16* Wt4 = (u16*)(w + 30 * MB);
  u16* Wto = (u16*)(w + 32 * MB);
  u16* z1 = (u16*)(w + 34 * MB);  // [bh][2048][64] bf16 projections
  u16* yh = (u16*)(w + 42 * MB);
  u16* xh = (u16*)(w + 50 * MB);
  u16* z2 = (u16*)(w + 58 * MB);

  cvt_kernel<<<4096, 256, 0, stream>>>(x, xb);
  cvt_kernel<<<4096, 256, 0, stream>>>(y, yb);
  cvt_kernel<<<4096, 256, 0, stream>>>(z, zb);
  dim3 tg(32, 32);
  wtT_kernel<<<tg, 256, 0, stream>>>(w_sa1, Wt1);
  wtT_kernel<<<tg, 256, 0, stream>>>(w_sa2, Wt2);
  wtT_kernel<<<tg, 256, 0, stream>>>(w_se1, Wt3);
  wtT_kernel<<<tg, 256, 0, stream>>>(w_se2, Wt4);
  wtT_kernel<<<tg, 256, 0, stream>>>(w_out, Wto);
  dim3 gg(32, 8);
  // z1 carries the attention scale d^-0.5 = 0.125 (free in the epilogue)
  gemm128<0><<<gg, 256, 0, stream>>>(zb, Wt1, z1, nullptr, 4096, 1024, 0.125f);
  gemm128<0><<<gg, 256, 0, stream>>>(yb, Wt2, yh, nullptr, 4096, 1024, 1.0f);
  gemm128<0><<<gg, 256, 0, stream>>>(xb, Wt3, xh, nullptr, 4096, 1024, 1.0f);
  gemm128<0><<<gg, 256, 0, stream>>>(zb, Wt4, z2, nullptr, 4096, 1024, 1.0f);
  // spatial attention -> comb (overwrites xb region; xb is dead now)
  attn_sp<<<512, 256, 0, stream>>>(z1, yh, xh, comb);
  // channel attention
  chan_part<<<dim3(8, 32), 256, 0, stream>>>(xh, z2, scpart);
  chan_sm<<<32, 64, 0, stream>>>(scpart, secm);
  combine_k<<<16384, 256, 0, stream>>>(yh, secm, comb);
  // output projection + bias -> d_out (fp32)
  gemm128<1><<<gg, 256, 0, stream>>>(comb, Wto, d_out, b_out, 4096, 1024, 1.0f);
}

// Round 9
// 367.081 us; speedup vs baseline: 1.3351x; 1.1786x over previous
//
#include <hip/hip_runtime.h>

// Problem constants: DIM=1024, HEADS=16, DIM_HEAD=64, INNER=1024, B=2, N=2048.
// M = B*N = 4096 rows for all GEMMs; K = N_cols = 1024.

typedef unsigned short u16;
typedef unsigned int u32;
typedef __attribute__((ext_vector_type(8))) short bf16x8;  // 8 bf16 (4 VGPRs)
typedef __attribute__((ext_vector_type(4))) float f32x4;

#define DEV __device__ __forceinline__

DEV u16 f2bf(float f) {  // round-to-nearest-even f32 -> bf16
  unsigned u = __builtin_bit_cast(unsigned, f);
  u += 0x7FFFu + ((u >> 16) & 1u);
  return (u16)(u >> 16);
}
DEV float bf2f(u16 h) {
  unsigned u = ((unsigned)h) << 16;
  return __builtin_bit_cast(float, u);
}

DEV void gld16(const void* g, void* l) {  // async global->LDS, 16B/lane
  __builtin_amdgcn_global_load_lds(
      (const __attribute__((address_space(1))) unsigned int*)g,
      (__attribute__((address_space(3))) unsigned int*)l, 16, 0, 0);
}

union B8 {
  u32 w[4];
  bf16x8 v;
};

// ---------------------------------------------------------------- cvt f32->bf16
__global__ __launch_bounds__(256) void cvt_kernel(const float* __restrict__ in,
                                                  u16* __restrict__ out) {
  const int i = blockIdx.x * 256 + threadIdx.x;  // one float4 per thread
  float4 v = ((const float4*)in)[i];
  u16 o[4] = {f2bf(v.x), f2bf(v.y), f2bf(v.z), f2bf(v.w)};
  ((ushort4*)out)[i] = *(const ushort4*)o;
}

// ------------------------------------------- weight transpose+convert (1024^2)
__global__ __launch_bounds__(256) void wtT_kernel(const float* __restrict__ W,
                                                  u16* __restrict__ Wt) {
  __shared__ float tile[32][33];
  const int k0 = blockIdx.x * 32, c0 = blockIdx.y * 32;
  const int tx = threadIdx.x & 31, ty = threadIdx.x >> 5;  // 32 x 8
#pragma unroll
  for (int i = 0; i < 32; i += 8)
    tile[ty + i][tx] = W[(size_t)(k0 + ty + i) * 1024 + c0 + tx];
  __syncthreads();
#pragma unroll
  for (int i = 0; i < 32; i += 8)
    Wt[(size_t)(c0 + ty + i) * 1024 + k0 + tx] = f2bf(tile[tx][ty + i]);
}

// --------------------------------------------------- fused projection GEMM 128^2
// One dispatch for all 4 projections. Bt = [4096][1024] (Wt1|Wt2|Wt3|Wt4 rows
// contiguous); out = z1 base with z1|yh|xh|z2 contiguous (4M u16 apart).
// proj = by>>3 selects A in {z,y,x,z} and the output slice. Grid 32x32 = 1024
// blocks = 4 blocks/CU (vs 1/CU for four separate dispatches).
__global__ __launch_bounds__(256, 2) void gemm_proj(const u16* __restrict__ Az,
                                                    const u16* __restrict__ Ay,
                                                    const u16* __restrict__ Ax,
                                                    const u16* __restrict__ Bt,
                                                    u16* __restrict__ out) {
  __shared__ __align__(16) u16 Ab[128 * 32];
  __shared__ __align__(16) u16 Bb[128 * 32];
  const int tid = threadIdx.x;
  const int lane = tid & 63, wv = tid >> 6;
  const int g = lane >> 4, c = lane & 15;
  const int m0 = blockIdx.x * 128, n0 = blockIdx.y * 128;  // n0 global in [0,4096)
  const int proj = blockIdx.y >> 3;
  const u16* A = (proj == 1) ? Ay : (proj == 2) ? Ax : Az;  // 0,3 -> z
  const float oscale = (proj == 0) ? 0.125f : 1.0f;         // attn scale on z1
  const int wr = (wv >> 1) * 64, wc = (wv & 1) * 64;
  const int srow = lane >> 2, scol = (lane & 3) * 8;  // staging map

  f32x4 acc[4][4];
#pragma unroll
  for (int i = 0; i < 4; i++)
#pragma unroll
    for (int j = 0; j < 4; j++) acc[i][j] = f32x4{0.f, 0.f, 0.f, 0.f};

  for (int k0 = 0; k0 < 1024; k0 += 32) {
    __syncthreads();
#pragma unroll
    for (int i = 0; i < 2; i++) {
      const int ch = wv + i * 4;  // wave-uniform chunk id; LDS dest = base+lane*16
      gld16(&A[(size_t)(m0 + ch * 16 + srow) * 1024 + k0 + scol], &Ab[ch * 512]);
      gld16(&Bt[(size_t)(n0 + ch * 16 + srow) * 1024 + k0 + scol], &Bb[ch * 512]);
    }
    __syncthreads();
    bf16x8 af[4], bf[4];
#pragma unroll
    for (int mi = 0; mi < 4; mi++)
      af[mi] = *(const bf16x8*)&Ab[(wr + mi * 16 + c) * 32 + g * 8];
#pragma unroll
    for (int ni = 0; ni < 4; ni++)
      bf[ni] = *(const bf16x8*)&Bb[(wc + ni * 16 + c) * 32 + g * 8];
#pragma unroll
    for (int mi = 0; mi < 4; mi++)
#pragma unroll
      for (int ni = 0; ni < 4; ni++)
        acc[mi][ni] = __builtin_amdgcn_mfma_f32_16x16x32_bf16(af[mi], bf[ni],
                                                              acc[mi][ni], 0, 0, 0);
  }

#pragma unroll
  for (int mi = 0; mi < 4; mi++)
#pragma unroll
    for (int ni = 0; ni < 4; ni++)
#pragma unroll
      for (int r = 0; r < 4; r++) {
        const int m = m0 + wr + mi * 16 + g * 4 + r;   // C row = (lane>>4)*4+reg
        const int ng = n0 + wc + ni * 16 + c;          // C col (global)
        const int nl = ng & 1023;                      // col within projection
        const int b = m >> 11, nn = m & 2047, h = nl >> 6, d = nl & 63;
        out[(size_t)proj * 4194304 +
            ((((size_t)(b * 16 + h)) * 2048 + nn) << 6) + d] =
            f2bf(acc[mi][ni][r] * oscale);
      }
}

// ------------------------------------------------- output projection GEMM 128^2
// C[m][n] = sum_k A[m][k] * Wt[n][k], fp32 out + bias.
__global__ __launch_bounds__(256, 2) void gemm_out(const u16* __restrict__ A,
                                                   const u16* __restrict__ Bt,
                                                   float* __restrict__ Cout,
                                                   const float* __restrict__ bias) {
  __shared__ __align__(16) u16 Ab[128 * 32];
  __shared__ __align__(16) u16 Bb[128 * 32];
  const int tid = threadIdx.x;
  const int lane = tid & 63, wv = tid >> 6;
  const int g = lane >> 4, c = lane & 15;
  const int m0 = blockIdx.x * 128, n0 = blockIdx.y * 128;
  const int wr = (wv >> 1) * 64, wc = (wv & 1) * 64;
  const int srow = lane >> 2, scol = (lane & 3) * 8;

  f32x4 acc[4][4];
#pragma unroll
  for (int i = 0; i < 4; i++)
#pragma unroll
    for (int j = 0; j < 4; j++) acc[i][j] = f32x4{0.f, 0.f, 0.f, 0.f};

  for (int k0 = 0; k0 < 1024; k0 += 32) {
    __syncthreads();
#pragma unroll
    for (int i = 0; i < 2; i++) {
      const int ch = wv + i * 4;
      gld16(&A[(size_t)(m0 + ch * 16 + srow) * 1024 + k0 + scol], &Ab[ch * 512]);
      gld16(&Bt[(size_t)(n0 + ch * 16 + srow) * 1024 + k0 + scol], &Bb[ch * 512]);
    }
    __syncthreads();
    bf16x8 af[4], bf[4];
#pragma unroll
    for (int mi = 0; mi < 4; mi++)
      af[mi] = *(const bf16x8*)&Ab[(wr + mi * 16 + c) * 32 + g * 8];
#pragma unroll
    for (int ni = 0; ni < 4; ni++)
      bf[ni] = *(const bf16x8*)&Bb[(wc + ni * 16 + c) * 32 + g * 8];
#pragma unroll
    for (int mi = 0; mi < 4; mi++)
#pragma unroll
      for (int ni = 0; ni < 4; ni++)
        acc[mi][ni] = __builtin_amdgcn_mfma_f32_16x16x32_bf16(af[mi], bf[ni],
                                                              acc[mi][ni], 0, 0, 0);
  }

#pragma unroll
  for (int mi = 0; mi < 4; mi++)
#pragma unroll
    for (int ni = 0; ni < 4; ni++)
#pragma unroll
      for (int r = 0; r < 4; r++) {
        const int m = m0 + wr + mi * 16 + g * 4 + r;
        const int n = n0 + wc + ni * 16 + c;
        Cout[(size_t)m * 1024 + n] = acc[mi][ni][r] + bias[n];
      }
}

// ------------------------------------------------------- spatial flash attention
// Swapped-QK flash attention with defer-max (T13). Per (b,h):
// out1 = softmax(z1 yh^T)·xh (scale pre-folded into z1). Q=z1, K=yh, V=xh.
// Block = 128 q rows (4 waves x 32 q). KVB=64. S^T = mfma(Kfrag, Qfrag) so each
// lane holds a q-row's scores -> in-register softmax; P rebuilt via bpermute.
// LDS swizzle: chunk ^= (row&7) ^ ((row>>3)&7).
__global__ __launch_bounds__(256, 2) void attn_sp(const u16* __restrict__ Q,
                                                  const u16* __restrict__ K,
                                                  const u16* __restrict__ V,
                                                  u16* __restrict__ comb) {
  __shared__ __align__(16) u16 Kld[2][4096];
  __shared__ __align__(16) u16 Vld[2][4096];
  const int tid = threadIdx.x, lane = tid & 63, wv = tid >> 6;
  const int g = lane >> 4, c = lane & 15;
  const int bh = blockIdx.x & 31, qt = blockIdx.x >> 5;
  const size_t base = (size_t)bh * (2048 * 64);
  const int q0 = qt * 128 + wv * 32;
  const u16* Qp = Q + base;
  const u16* Kp = K + base;
  const u16* Vp = V + base;

  bf16x8 qf[2][2];
#pragma unroll
  for (int qb = 0; qb < 2; qb++)
#pragma unroll
    for (int kf = 0; kf < 2; kf++)
      qf[qb][kf] =
          *(const bf16x8*)&Qp[(size_t)(q0 + qb * 16 + c) * 64 + kf * 32 + g * 8];

  int ksrc[2], kbas[2];
#pragma unroll
  for (int t2 = 0; t2 < 2; t2++) {
    const int r = wv * 16 + t2 * 8 + (lane >> 3);
    const int ul = (lane & 7) ^ (lane >> 3) ^ ((wv * 2 + t2) & 7);
    ksrc[t2] = r * 64 + ul * 8;
    kbas[t2] = wv * 1024 + t2 * 512;
  }
  const int vd0 = (lane & 7) * 8;
  const int vkey0 = wv * 8 + (lane >> 3), vkey1 = 32 + vkey0;
  const int vx = lane & 7;

  f32x4 acc[2][4];
  float mrow[2] = {-3e38f, -3e38f}, lrow[2] = {0.f, 0.f};
#pragma unroll
  for (int qb = 0; qb < 2; qb++)
#pragma unroll
    for (int df = 0; df < 4; df++) acc[qb][df] = f32x4{0.f, 0.f, 0.f, 0.f};

  gld16(Kp + ksrc[0], &Kld[0][kbas[0]]);
  gld16(Kp + ksrc[1], &Kld[0][kbas[1]]);
  int4 vv0 = *(const int4*)&Vp[(size_t)vkey0 * 64 + vd0];
  int4 vv1 = *(const int4*)&Vp[(size_t)vkey1 * 64 + vd0];

  for (int t = 0; t < 32; ++t) {
    const int p = t & 1;
    u16* Kb = Kld[p];
    u16* Vb = Vld[p];
    __syncthreads();

    {
      const u16* vs = (const u16*)&vv0;
      const int ui = wv, si = vkey0 & 7;
#pragma unroll
      for (int j = 0; j < 8; j++)
        Vb[(vd0 + j) * 64 + (((ui ^ j ^ vx) & 7) << 3) + si] = vs[j];
    }
    {
      const u16* vs = (const u16*)&vv1;
      const int ui = 4 + wv, si = vkey1 & 7;
#pragma unroll
      for (int j = 0; j < 8; j++)
        Vb[(vd0 + j) * 64 + (((ui ^ j ^ vx) & 7) << 3) + si] = vs[j];
    }
    if (t < 31) {
      const u16* Kn = Kp + (t + 1) * 4096;
      gld16(Kn + ksrc[0], &Kld[p ^ 1][kbas[0]]);
      gld16(Kn + ksrc[1], &Kld[p ^ 1][kbas[1]]);
      const u16* Vn = Vp + (t + 1) * 4096;
      vv0 = *(const int4*)&Vn[vkey0 * 64 + vd0];
      vv1 = *(const int4*)&Vn[vkey1 * 64 + vd0];
    }

    f32x4 st[2][4];
#pragma unroll
    for (int qb = 0; qb < 2; qb++)
#pragma unroll
      for (int nf = 0; nf < 4; nf++) st[qb][nf] = f32x4{0.f, 0.f, 0.f, 0.f};
#pragma unroll
    for (int nf = 0; nf < 4; nf++)
#pragma unroll
      for (int kf = 0; kf < 2; kf++) {
        const int phys = (kf * 4 + g) ^ (c & 7) ^ ((nf * 2 + (c >> 3)) & 7);
        bf16x8 af =
            *(const bf16x8*)((const char*)Kb + ((nf * 16 + c) << 7) + (phys << 4));
        st[0][nf] = __builtin_amdgcn_mfma_f32_16x16x32_bf16(af, qf[0][kf],
                                                            st[0][nf], 0, 0, 0);
        st[1][nf] = __builtin_amdgcn_mfma_f32_16x16x32_bf16(af, qf[1][kf],
                                                            st[1][nf], 0, 0, 0);
      }

    // in-register online softmax with defer-max (T13, THR=8)
    u32 pk[2][4][2];
#pragma unroll
    for (int qb = 0; qb < 2; qb++) {
      float mt = -3e38f;
#pragma unroll
      for (int nf = 0; nf < 4; nf++)
#pragma unroll
        for (int r = 0; r < 4; r++) mt = fmaxf(mt, st[qb][nf][r]);
      mt = fmaxf(mt, __shfl_xor(mt, 16));
      mt = fmaxf(mt, __shfl_xor(mt, 32));
      float p_[4][4];
      float ps = 0.f;
      if (__all(mt <= mrow[qb] + 8.0f)) {
        // defer: keep old max, no O-rescale (P bounded by e^8, fp32 accum ok)
#pragma unroll
        for (int nf = 0; nf < 4; nf++)
#pragma unroll
          for (int r = 0; r < 4; r++) {
            p_[nf][r] = __expf(st[qb][nf][r] - mrow[qb]);
            ps += p_[nf][r];
          }
        ps += __shfl_xor(ps, 16);
        ps += __shfl_xor(ps, 32);
        lrow[qb] += ps;
      } else {
        const float mnew = fmaxf(mrow[qb], mt);
        const float fsc = __expf(mrow[qb] - mnew);
        mrow[qb] = mnew;
#pragma unroll
        for (int nf = 0; nf < 4; nf++)
#pragma unroll
          for (int r = 0; r < 4; r++) {
            p_[nf][r] = __expf(st[qb][nf][r] - mnew);
            ps += p_[nf][r];
          }
        ps += __shfl_xor(ps, 16);
        ps += __shfl_xor(ps, 32);
        lrow[qb] = lrow[qb] * fsc + ps;
        float fo[4];
#pragma unroll
        for (int r = 0; r < 4; r++) fo[r] = __shfl(fsc, 4 * g + r);
#pragma unroll
        for (int df = 0; df < 4; df++)
#pragma unroll
          for (int r = 0; r < 4; r++) acc[qb][df][r] *= fo[r];
      }
#pragma unroll
      for (int nf = 0; nf < 4; nf++) {
        pk[qb][nf][0] = (u32)f2bf(p_[nf][0]) | ((u32)f2bf(p_[nf][1]) << 16);
        pk[qb][nf][1] = (u32)f2bf(p_[nf][2]) | ((u32)f2bf(p_[nf][3]) << 16);
      }
    }
    __syncthreads();

    // PV: rebuild P A-fragments in-register (bpermute), O += P·V
#pragma unroll
    for (int kk = 0; kk < 2; kk++) {
      const int srcA = c + ((g & 1) << 5);
      const int srcB = srcA + 16;
      const bool hi = g >= 2;
      bf16x8 pf[2];
#pragma unroll
      for (int qb = 0; qb < 2; qb++) {
        B8 u;
        u32 a0 = (u32)__shfl((int)pk[qb][2 * kk + 0][0], srcA);
        u32 a1 = (u32)__shfl((int)pk[qb][2 * kk + 1][0], srcA);
        u.w[0] = hi ? a1 : a0;
        a0 = (u32)__shfl((int)pk[qb][2 * kk + 0][1], srcA);
        a1 = (u32)__shfl((int)pk[qb][2 * kk + 1][1], srcA);
        u.w[1] = hi ? a1 : a0;
        a0 = (u32)__shfl((int)pk[qb][2 * kk + 0][0], srcB);
        a1 = (u32)__shfl((int)pk[qb][2 * kk + 1][0], srcB);
        u.w[2] = hi ? a1 : a0;
        a0 = (u32)__shfl((int)pk[qb][2 * kk + 0][1], srcB);
        a1 = (u32)__shfl((int)pk[qb][2 * kk + 1][1], srcB);
        u.w[3] = hi ? a1 : a0;
        pf[qb] = u.v;
      }
#pragma unroll
      for (int df = 0; df < 4; df++) {
        const int phys = (kk * 4 + g) ^ (c & 7) ^ ((df * 2 + (c >> 3)) & 7);
        bf16x8 vf =
            *(const bf16x8*)((const char*)Vb + ((df * 16 + c) << 7) + (phys << 4));
        acc[0][df] = __builtin_amdgcn_mfma_f32_16x16x32_bf16(pf[0], vf,
                                                             acc[0][df], 0, 0, 0);
        acc[1][df] = __builtin_amdgcn_mfma_f32_16x16x32_bf16(pf[1], vf,
                                                             acc[1][df], 0, 0, 0);
      }
    }
  }

  const int b = bh >> 4, h = bh & 15;
#pragma unroll
  for (int qb = 0; qb < 2; qb++)
#pragma unroll
    for (int r = 0; r < 4; r++) {
      const float lr = __shfl(lrow[qb], 4 * g + r);
      const float inv = 1.f / lr;
      const int n = q0 + qb * 16 + g * 4 + r;
      const size_t off = ((size_t)(b * 2048 + n)) * 1024 + h * 64;
#pragma unroll
      for (int df = 0; df < 4; df++)
        comb[off + df * 16 + c] = f2bf(acc[qb][df][r] * inv);
    }
}

// --------------------------------------------- channel attention: partial scores
__global__ __launch_bounds__(256) void chan_part(const u16* __restrict__ Xh,
                                                 const u16* __restrict__ Z2,
                                                 float* __restrict__ part) {
  const int bh = blockIdx.y, sl = blockIdx.x;
  const size_t base = (size_t)bh * (2048 * 64);
  const int ti = threadIdx.x >> 4, tj = threadIdx.x & 15;
  float a[4][4];
#pragma unroll
  for (int u = 0; u < 4; u++)
#pragma unroll
    for (int v = 0; v < 4; v++) a[u][v] = 0.f;
  const int n0 = sl * 256;
  for (int n = 0; n < 256; n++) {
    ushort4 xv = *(const ushort4*)&Xh[base + (size_t)(n0 + n) * 64 + ti * 4];
    ushort4 zv = *(const ushort4*)&Z2[base + (size_t)(n0 + n) * 64 + tj * 4];
    float xf[4] = {bf2f(xv.x), bf2f(xv.y), bf2f(xv.z), bf2f(xv.w)};
    float zf[4] = {bf2f(zv.x), bf2f(zv.y), bf2f(zv.z), bf2f(zv.w)};
#pragma unroll
    for (int u = 0; u < 4; u++)
#pragma unroll
      for (int v = 0; v < 4; v++) a[u][v] += xf[u] * zf[v];
  }
  float* dst = part + ((size_t)bh * 8 + sl) * 4096;
#pragma unroll
  for (int u = 0; u < 4; u++)
#pragma unroll
    for (int v = 0; v < 4; v++) dst[(ti * 4 + u) * 64 + tj * 4 + v] = a[u][v];
}

// secm[bh][i][j] = softmax_j( sum_sl part * (1/256) )
__global__ __launch_bounds__(64) void chan_sm(const float* __restrict__ part,
                                              float* __restrict__ secm) {
  const int bh = blockIdx.x, r = threadIdx.x;
  float v[64];
#pragma unroll
  for (int j = 0; j < 64; j++) v[j] = 0.f;
  for (int sl = 0; sl < 8; sl++) {
    const float* p = part + ((size_t)bh * 8 + sl) * 4096 + r * 64;
#pragma unroll
    for (int j = 0; j < 64; j++) v[j] += p[j];
  }
  float mx = -1e30f;
#pragma unroll
  for (int j = 0; j < 64; j++) {
    v[j] *= (1.f / 256.f);  // scale(0.125) / (n/d = 32)
    mx = fmaxf(mx, v[j]);
  }
  float sum = 0.f;
#pragma unroll
  for (int j = 0; j < 64; j++) {
    v[j] = __expf(v[j] - mx);
    sum += v[j];
  }
  const float inv = 1.f / sum;
  float* o = secm + (size_t)bh * 4096 + r * 64;
#pragma unroll
  for (int j = 0; j < 64; j++) o[j] = v[j] * inv;
}

// comb[b][n][h*64+j] += sum_i yh[bh][n][i] * secm[bh][i][j]   (wave per row)
__global__ __launch_bounds__(256) void combine_k(const u16* __restrict__ Yh,
                                                 const float* __restrict__ secm,
                                                 u16* __restrict__ comb) {
  const int tid = threadIdx.x, lane = tid & 63, wv = tid >> 6;
  const size_t row = (size_t)blockIdx.x * 4 + wv;  // bh*2048 + n
  const int bh = (int)(row >> 11), n = (int)(row & 2047);
  const int b = bh >> 4, h = bh & 15;
  const float yv = bf2f(Yh[row * 64 + lane]);
  const float* S = secm + (size_t)bh * 4096;
  float acc2 = 0.f;
#pragma unroll 8
  for (int i = 0; i < 64; i++) acc2 += __shfl(yv, i) * S[i * 64 + lane];
  const size_t off = ((size_t)(b * 2048 + n)) * 1024 + (size_t)h * 64 + lane;
  comb[off] = f2bf(bf2f(comb[off]) + acc2);
}

// ---------------------------------------------------------------------- launch
extern "C" void kernel_launch(void* const* d_in, const int* in_sizes, int n_in,
                              void* d_out, int out_size, void* d_ws, size_t ws_size,
                              hipStream_t stream) {
  (void)in_sizes; (void)n_in; (void)out_size; (void)ws_size;
  const float* x = (const float*)d_in[0];
  const float* y = (const float*)d_in[1];
  const float* z = (const float*)d_in[2];
  const float* w_sa1 = (const float*)d_in[3];
  const float* w_sa2 = (const float*)d_in[4];
  const float* w_se1 = (const float*)d_in[5];
  const float* w_se2 = (const float*)d_in[6];
  const float* w_out = (const float*)d_in[7];
  const float* b_out = (const float*)d_in[8];

  char* w = (char*)d_ws;
  const size_t MB = (size_t)1 << 20;
  u16* xb = (u16*)(w + 0);        // x bf16; later reused as comb
  u16* comb = xb;                 // attention out1+out2 (bf16, [b][n][1024])
  u16* yb = (u16*)(w + 8 * MB);   // y bf16; later reused as chan partials
  float* scpart = (float*)(w + 8 * MB);
  u16* zb = (u16*)(w + 16 * MB);  // z bf16; later reused as secm
  float* secm = (float*)(w + 16 * MB);
  u16* Wt1 = (u16*)(w + 24 * MB);  // Wt1..Wt4 contiguous = fused B [4096][1024]
  u16* Wt2 = (u16*)(w + 26 * MB);
  u16* Wt3 = (u16*)(w + 28 * MB);
  u16* Wt4 = (u16*)(w + 30 * MB);
  u16* Wto = (u16*)(w + 32 * MB);
  u16* z1 = (u16*)(w + 34 * MB);  // z1|yh|xh|z2 contiguous, 4M u16 apart
  u16* yh = (u16*)(w + 42 * MB);
  u16* xh = (u16*)(w + 50 * MB);
  u16* z2 = (u16*)(w + 58 * MB);

  cvt_kernel<<<4096, 256, 0, stream>>>(x, xb);
  cvt_kernel<<<4096, 256, 0, stream>>>(y, yb);
  cvt_kernel<<<4096, 256, 0, stream>>>(z, zb);
  dim3 tg(32, 32);
  wtT_kernel<<<tg, 256, 0, stream>>>(w_sa1, Wt1);
  wtT_kernel<<<tg, 256, 0, stream>>>(w_sa2, Wt2);
  wtT_kernel<<<tg, 256, 0, stream>>>(w_se1, Wt3);
  wtT_kernel<<<tg, 256, 0, stream>>>(w_se2, Wt4);
  wtT_kernel<<<tg, 256, 0, stream>>>(w_out, Wto);
  // fused 4-projection GEMM: grid 32x32 = 1024 blocks (4/CU)
  dim3 gp(32, 32);
  gemm_proj<<<gp, 256, 0, stream>>>(zb, yb, xb, Wt1, z1);
  // spatial attention -> comb (overwrites xb region; xb input is dead now)
  attn_sp<<<512, 256, 0, stream>>>(z1, yh, xh, comb);
  // channel attention
  chan_part<<<dim3(8, 32), 256, 0, stream>>>(xh, z2, scpart);
  chan_sm<<<32, 64, 0, stream>>>(scpart, secm);
  combine_k<<<16384, 256, 0, stream>>>(yh, secm, comb);
  // output projection + bias -> d_out (fp32)
  dim3 gg(32, 8);
  gemm_out<<<gg, 256, 0, stream>>>(comb, Wto, (float*)d_out, b_out);
}